// Round 6
// baseline (231.911 us; speedup 1.0000x reference)
//
#include <hip/hip_runtime.h>
#include <hip/hip_bf16.h>

// HierarchicalRouter: x[16384,2048] fp32, group_gate_w[8,2048], expert_gate_w[64,2048]
// out = concat(valid_mask[16384,64] as 0/1 float, normalized_weights[16384,64] float)
//
// f16-MFMA with exact split: v = h + l/2048 (h=fp16(v), l=fp16((v-h)*2048));
// logit = acc_hh + acc_cross/2048 (3 MFMA passes, error ~2^-24 — below fp32 wobble,
// safe for the prob>=1/8 mask thresholds; R5 passed with absmax 9.8e-4).
//
// R5 post-mortem: weights were re-split from fp32 by EVERY block (~42M redundant
// element-splits ≈ 20 us of VALU chip-wide) and 1 block/CU exposed every per-chunk
// vmcnt/barrier stall. R6:
//   (1) prep kernel splits weights ONCE into d_ws (655 KB), stored pre-swizzled in
//       mfma_f32_16x16x32_f16 A-fragment order -> main W staging is a pure copy.
//   (2) 512 blocks x 512 thr, 32 tokens/block, KC=64, dbuf LDS 60 KB -> 2 blocks/CU
//       (16 waves/CU) so co-resident blocks hide each other's barrier stalls.
// Wave = (token-tile tt=w&1, K-half s2=(w>>1)&1, gate-half gh=w>>2: {0,1,2} / {3,4}).
// Per wave per chunk: <=9 MFMAs, all LDS reads ds_read_b128 at padded strides.
// Epilogue: pairwise K-reduce via LDS, per-token dual softmax + hierarchical mask
// (proven fp32 code), coalesced float4 stores.

#define NT 16384
#define NE 2048
#define NCHUNK 32        // chunks of KC=64

#define QS 272           // q-row stride (16x16B + 16 pad)
#define PL 1088          // h -> l plane offset (4*QS)
#define FP 2208          // fragment-pair stride (2*PL + 32 pad)
#define XB 22080         // X region base (W region = 10 fragment-pairs)
#define BUFSZ 30912      // W 22080 + X 8832
#define LDS_BYTES 61824  // 2 * BUFSZ -> 2 blocks/CU

typedef _Float16 v8h __attribute__((ext_vector_type(8)));
typedef float    v4f __attribute__((ext_vector_type(4)));

// ---- prep: split 80 gate-rows (64 expert + 8 group + 8 zero-pad) into fragment-order
// Wbuf units: u=(((g4*64+gk)*4+q)*16+gr), 32 B each: [8 x f16 h][8 x f16 l]. 655360 B.
__global__ __launch_bounds__(256)
void prep(const float* __restrict__ gw, const float* __restrict__ ew,
          float* __restrict__ Wbuf)
{
    const int u = blockIdx.x * 256 + threadIdx.x;          // 0..20479
    const int g4 = u >> 12, gk = (u >> 6) & 63, q = (u >> 4) & 3, gr = u & 15;
    const int gate = g4 * 16 + gr;
    const int k = gk * 32 + q * 8;
    float v[8];
    if (gate < 64) {
        float4 a = *(const float4*)(ew + (size_t)gate * NE + k);
        float4 b = *(const float4*)(ew + (size_t)gate * NE + k + 4);
        v[0]=a.x; v[1]=a.y; v[2]=a.z; v[3]=a.w; v[4]=b.x; v[5]=b.y; v[6]=b.z; v[7]=b.w;
    } else if (gate < 72) {
        float4 a = *(const float4*)(gw + (size_t)(gate - 64) * NE + k);
        float4 b = *(const float4*)(gw + (size_t)(gate - 64) * NE + k + 4);
        v[0]=a.x; v[1]=a.y; v[2]=a.z; v[3]=a.w; v[4]=b.x; v[5]=b.y; v[6]=b.z; v[7]=b.w;
    } else {
        #pragma unroll
        for (int j = 0; j < 8; ++j) v[j] = 0.f;
    }
    v8h h, l;
    #pragma unroll
    for (int j = 0; j < 8; ++j) {
        _Float16 hh = (_Float16)v[j];
        h[j] = hh;
        l[j] = (_Float16)((v[j] - (float)hh) * 2048.0f);
    }
    char* p = (char*)Wbuf + (size_t)u * 32;
    *(v8h*)p        = h;
    *(v8h*)(p + 16) = l;
}

__global__ __launch_bounds__(512, 4)
void router(const float* __restrict__ x, const float* __restrict__ Wbuf,
            float* __restrict__ out)
{
    __shared__ __align__(16) char sm[LDS_BYTES];
    const int tid  = threadIdx.x;
    const int lane = tid & 63;
    const int w    = tid >> 6;
    const int t0   = blockIdx.x * 32;

    // ---- staging descriptors (all wave-uniform roles: boundaries at 128/384) ----
    // slot0: W unit s=tid (0..511). slot1: tid<128 -> W unit 512+tid; 128<=tid<384 -> X.
    const char* w0src; int who0;
    {
        int g4 = tid >> 7, lks = (tid >> 6) & 1, q = (tid >> 4) & 3, gr = tid & 15;
        w0src = (const char*)Wbuf + (size_t)((((g4*64 + lks)*4 + q)*16 + gr) * 32);
        who0  = (g4*2 + lks)*FP + q*QS + gr*16;
    }
    const bool s1W = (tid < 128), s1X = (tid >= 128 && tid < 384);
    const char* w1src = nullptr; int who1 = 0;
    const float* xsrc = nullptr; int xho = 0;
    if (s1W) {
        int s = tid + 512;
        int g4 = s >> 7, lks = (s >> 6) & 1, q = (s >> 4) & 3, gr = s & 15;
        w1src = (const char*)Wbuf + (size_t)((((g4*64 + lks)*4 + q)*16 + gr) * 32);
        who1  = (g4*2 + lks)*FP + q*QS + gr*16;
    } else if (s1X) {
        int i2 = tid - 128;
        int q = i2 & 3, tr = (i2 >> 2) & 15, lks = (i2 >> 6) & 1, tt = (i2 >> 7) & 1;
        xsrc = x + (size_t)(t0 + tt*16 + tr) * NE + lks*32 + q*8;
        xho  = XB + (tt*2 + lks)*FP + q*QS + tr*16;
    }

    float4 wh0, wl0, wh1, wl1, xa, xb;
    auto stage_load = [&](int c) {
        const char* p0 = w0src + c * 4096;
        wh0 = *(const float4*)p0;  wl0 = *(const float4*)(p0 + 16);
        if (s1W) {
            const char* p1 = w1src + c * 4096;
            wh1 = *(const float4*)p1;  wl1 = *(const float4*)(p1 + 16);
        } else if (s1X) {
            xa = *(const float4*)(xsrc + c * 64);
            xb = *(const float4*)(xsrc + c * 64 + 4);
        }
    };
    auto stage_commit = [&](int buf) {
        const int bb = buf * BUFSZ;
        *(float4*)(sm + bb + who0)      = wh0;
        *(float4*)(sm + bb + who0 + PL) = wl0;
        if (s1W) {
            *(float4*)(sm + bb + who1)      = wh1;
            *(float4*)(sm + bb + who1 + PL) = wl1;
        } else if (s1X) {
            float v[8] = {xa.x, xa.y, xa.z, xa.w, xb.x, xb.y, xb.z, xb.w};
            v8h h, l;
            #pragma unroll
            for (int j = 0; j < 8; ++j) {
                _Float16 hh = (_Float16)v[j];
                h[j] = hh;
                l[j] = (_Float16)((v[j] - (float)hh) * 2048.0f);
            }
            *(v8h*)(sm + bb + xho)      = h;
            *(v8h*)(sm + bb + xho + PL) = l;
        }
    };

    // ---- compute mapping ----
    const int tt = w & 1, s2 = (w >> 1) & 1, gh = w >> 2;
    const int ng = gh ? 2 : 3, gbase = gh ? 3 : 0;
    const int rdo = (lane >> 4) * QS + (lane & 15) * 16;

    v4f accHH[3], accC[3];
    #pragma unroll
    for (int g = 0; g < 3; ++g) { accHH[g] = (v4f)(0.f); accC[g] = (v4f)(0.f); }

    // ---- pipeline: one barrier per chunk; loads for c+1 in flight over barrier+compute ----
    stage_load(0);
    stage_commit(0);
    for (int c = 0; c < NCHUNK; ++c) {
        if (c + 1 < NCHUNK) stage_load(c + 1);
        __syncthreads();
        {
            const int bb = (c & 1) * BUFSZ;
            const char* xbp = sm + bb + XB + (tt*2 + s2)*FP + rdo;
            v8h Bh = *(const v8h*)xbp;
            v8h Bl = *(const v8h*)(xbp + PL);
            #pragma unroll
            for (int gi = 0; gi < 3; ++gi) {
                if (gi < ng) {
                    const char* wbp = sm + bb + ((gbase + gi)*2 + s2)*FP + rdo;
                    v8h Ah = *(const v8h*)wbp;
                    v8h Al = *(const v8h*)(wbp + PL);
                    accHH[gi] = __builtin_amdgcn_mfma_f32_16x16x32_f16(Ah, Bh, accHH[gi], 0, 0, 0);
                    accC[gi]  = __builtin_amdgcn_mfma_f32_16x16x32_f16(Ah, Bl, accC[gi], 0, 0, 0);
                    accC[gi]  = __builtin_amdgcn_mfma_f32_16x16x32_f16(Al, Bh, accC[gi], 0, 0, 0);
                }
            }
        }
        if (c + 1 < NCHUNK) stage_commit((c + 1) & 1);
    }

    // ---- K-reduce: s2=1 writes partials (buf0 region, last compute used buf1) ----
    float part[3][4];
    #pragma unroll
    for (int gi = 0; gi < 3; ++gi)
        #pragma unroll
        for (int r = 0; r < 4; ++r)
            part[gi][r] = accHH[gi][r] + accC[gi][r] * (1.0f / 2048.0f);

    float* red = (float*)sm;                 // [ (tt*5+g4)*4+r ][ lane ] = 10240 B
    if (s2 == 1) {
        #pragma unroll
        for (int gi = 0; gi < 3; ++gi)
            if (gi < ng)
                #pragma unroll
                for (int r = 0; r < 4; ++r)
                    red[((tt*5 + gbase + gi)*4 + r)*64 + lane] = part[gi][r];
    }
    __syncthreads();
    float* la = (float*)(sm + 12288);        // [32 tokens][80 gates]
    if (s2 == 0) {
        #pragma unroll
        for (int gi = 0; gi < 3; ++gi)
            if (gi < ng)
                #pragma unroll
                for (int r = 0; r < 4; ++r) {
                    float v = part[gi][r] + red[((tt*5 + gbase + gi)*4 + r)*64 + lane];
                    int gate  = (gbase + gi)*16 + (lane >> 4)*4 + r;   // D row
                    int token = tt*16 + (lane & 15);                   // D col
                    la[token*80 + gate] = v;
                }
    }
    __syncthreads();

    // ---- per-token dual softmax + hierarchical mask (threads 0..31) ----
    if (tid < 32) {
        const float* lg = la + tid * 80;     // [0..63]=experts, [64..71]=groups
        float* M = (float*)(sm + 24576) + tid * 64;
        float* W = (float*)(sm + 32768) + tid * 64;

        float gpb[8];
        float gmax = lg[64];
        #pragma unroll
        for (int g = 1; g < 8; ++g) gmax = fmaxf(gmax, lg[64 + g]);
        float gsum = 0.f;
        #pragma unroll
        for (int g = 0; g < 8; ++g) { gpb[g] = __expf(lg[64 + g] - gmax); gsum += gpb[g]; }
        const float ginv = 1.f / gsum;

        float sel[64];
        float wsum = 0.f;
        #pragma unroll
        for (int g = 0; g < 8; ++g) {
            const float gp_ = gpb[g] * ginv;
            float emax = lg[g * 8];
            #pragma unroll
            for (int j = 1; j < 8; ++j) emax = fmaxf(emax, lg[g * 8 + j]);
            float ep[8]; float esum = 0.f;
            #pragma unroll
            for (int j = 0; j < 8; ++j) { ep[j] = __expf(lg[g * 8 + j] - emax); esum += ep[j]; }
            const float einv = 1.f / esum;
            const bool gm = gp_ >= 0.125f;
            #pragma unroll
            for (int j = 0; j < 8; ++j) {
                const float pe = ep[j] * einv;
                const bool v = gm && (pe >= 0.125f);
                const float ww = v ? gp_ * pe : 0.f;
                M[g * 8 + j] = v ? 1.f : 0.f;
                sel[g * 8 + j] = ww;
                wsum += ww;
            }
        }
        const float inv = 1.f / fmaxf(wsum, 1e-9f);
        #pragma unroll
        for (int e = 0; e < 64; ++e) W[e] = sel[e] * inv;
    }
    __syncthreads();

    // ---- coalesced stores: each plane = 32 tok x 64 = 512 float4 ----
    const float4* M4 = (const float4*)(sm + 24576);
    const float4* W4 = (const float4*)(sm + 32768);
    float4* o0 = (float4*)(out + (size_t)t0 * 64);
    float4* o1 = (float4*)(out + (size_t)NT * 64 + (size_t)t0 * 64);
    o0[tid] = M4[tid];
    o1[tid] = W4[tid];
}

extern "C" void kernel_launch(void* const* d_in, const int* in_sizes, int n_in,
                              void* d_out, int out_size, void* d_ws, size_t ws_size,
                              hipStream_t stream) {
    const float* x  = (const float*)d_in[0];
    const float* gw = (const float*)d_in[1];
    const float* ew = (const float*)d_in[2];
    float* out  = (float*)d_out;
    float* Wbuf = (float*)d_ws;              // 655360 B used

    prep<<<dim3(80),  dim3(256), 0, stream>>>(gw, ew, Wbuf);
    router<<<dim3(NT / 32), dim3(512), 0, stream>>>(x, Wbuf, out);
}

// Round 8
// 218.666 us; speedup vs baseline: 1.0606x; 1.0606x over previous
//
#include <hip/hip_runtime.h>
#include <hip/hip_bf16.h>

// HierarchicalRouter: x[16384,2048] fp32, group_gate_w[8,2048], expert_gate_w[64,2048]
// out = concat(valid_mask[16384,64] as 0/1 float, normalized_weights[16384,64] float)
//
// f16-MFMA with exact split: v = h + l/2048; logit = acc_hh + acc_cross/2048
// (error ~2^-21 rel — far below the prob>=1/8 mask margins; R5/R6 passed at ~1e-3).
//
// Barrier-free K-loop (R7 structure): a lane's mfma_16x16x32_f16 B-fragment is
// x[lane&15][k0+(lane>>4)*8 ..+7] = 32 CONTIGUOUS bytes of one x row -> loaded
// straight from global (wave = 16 full 128B lines), split to h/l in registers.
// A-fragments pre-split by prep into Wbuf (L2-resident). K-loop = pure register
// dataflow, per-wave self-paced, x prefetched 1 k-group ahead.
// 256 blocks x 512 thr. Block = 64 tokens; wave = (K-quarter s2=w>>1, token-half
// th=w&1) -> 2 token-tiles x 5 gate-tiles, 30 MFMA / 14 loads per k-group.
//
// R7 bug fixed here: reduce-tree step 4 read slot wq=th (stale s2=1 partials from
// step 1) instead of slot 2+th (s2=2's q2+q3 sum) -> logits = q0+2*q1, absmax 1.0.
// Macros now take the slot index explicitly; step 3/4 use slot 2+th.

#define NT 16384
#define NE 2048

typedef _Float16 v8h __attribute__((ext_vector_type(8)));
typedef float    v4f __attribute__((ext_vector_type(4)));

// ---- prep: split 80 gate-rows (64 expert + 8 group + 8 zero-pad) once ----
// unit u = ((g4*64+gk)*4+q)*16+gr, 32 B: [16B h][16B l] of W[g4*16+gr][gk*32+q*8..+7]
__global__ __launch_bounds__(256)
void prep(const float* __restrict__ gw, const float* __restrict__ ew,
          float* __restrict__ Wbuf)
{
    const int u = blockIdx.x * 256 + threadIdx.x;          // 0..20479
    const int g4 = u >> 12, gk = (u >> 6) & 63, q = (u >> 4) & 3, gr = u & 15;
    const int gate = g4 * 16 + gr;
    const int k = gk * 32 + q * 8;
    float v[8];
    if (gate < 64) {
        float4 a = *(const float4*)(ew + (size_t)gate * NE + k);
        float4 b = *(const float4*)(ew + (size_t)gate * NE + k + 4);
        v[0]=a.x; v[1]=a.y; v[2]=a.z; v[3]=a.w; v[4]=b.x; v[5]=b.y; v[6]=b.z; v[7]=b.w;
    } else if (gate < 72) {
        float4 a = *(const float4*)(gw + (size_t)(gate - 64) * NE + k);
        float4 b = *(const float4*)(gw + (size_t)(gate - 64) * NE + k + 4);
        v[0]=a.x; v[1]=a.y; v[2]=a.z; v[3]=a.w; v[4]=b.x; v[5]=b.y; v[6]=b.z; v[7]=b.w;
    } else {
        #pragma unroll
        for (int j = 0; j < 8; ++j) v[j] = 0.f;
    }
    v8h h, l;
    #pragma unroll
    for (int j = 0; j < 8; ++j) {
        _Float16 hh = (_Float16)v[j];
        h[j] = hh;
        l[j] = (_Float16)((v[j] - (float)hh) * 2048.0f);
    }
    char* p = (char*)Wbuf + (size_t)u * 32;
    *(v8h*)p        = h;
    *(v8h*)(p + 16) = l;
}

// LDS float offsets
#define P_BASE  0        // reduce buffer: 10 x 4 slots x 64 lanes x float4 = 10240 floats
#define LA_BASE 10240    // logits [64 tok][81] = 5184 floats
#define M_BASE  15424    // mask  [64][64] = 4096
#define W_BASE  19520    // weights [64][64] = 4096
#define SM_FLOATS 23616  // 94464 B

__global__ __launch_bounds__(512, 2)
void router(const float* __restrict__ x, const float* __restrict__ Wbuf,
            float* __restrict__ out)
{
    __shared__ __align__(16) float sm[SM_FLOATS];
    const int tid  = threadIdx.x;
    const int lane = tid & 63;
    const int w    = tid >> 6;
    const int s2   = w >> 1;           // K-quarter (512 K each)
    const int th   = w & 1;            // token-half (2 tiles of 16)
    const int t0   = blockIdx.x * 64;
    const int n    = lane & 15;        // token (B) / gate (A) row within tile
    const int q    = lane >> 4;        // k-subgroup: k elems q*8..q*8+7

    // x row pointers for the wave's two token-tiles
    const float* xr0 = x + (size_t)(t0 + th * 32 + n) * NE + s2 * 512 + q * 8;
    const float* xr1 = xr0 + (size_t)16 * NE;
    // W fragment base
    const char* wbp = (const char*)Wbuf;
    const int   wlo = q * 512 + n * 32;

    v4f aHH[2][5], aC[2][5];
    #pragma unroll
    for (int ti = 0; ti < 2; ++ti)
        #pragma unroll
        for (int g = 0; g < 5; ++g) { aHH[ti][g] = (v4f)(0.f); aC[ti][g] = (v4f)(0.f); }

    float4 xc[2][2], xn[2][2];
    xc[0][0] = *(const float4*)(xr0);      xc[0][1] = *(const float4*)(xr0 + 4);
    xc[1][0] = *(const float4*)(xr1);      xc[1][1] = *(const float4*)(xr1 + 4);

    for (int j = 0; j < 16; ++j) {
        const int gk = s2 * 16 + j;
        // W loads for this k-group (L2-hot; latency covered by split VALU below)
        v8h Wh[5], Wl[5];
        #pragma unroll
        for (int g = 0; g < 5; ++g) {
            const char* p = wbp + (size_t)(g * 64 + gk) * 2048 + wlo;
            Wh[g] = *(const v8h*)p;
            Wl[g] = *(const v8h*)(p + 16);
        }
        // x prefetch for k-group j+1 (HBM latency hidden across this body)
        if (j + 1 < 16) {
            const float* p0 = xr0 + (j + 1) * 32;
            const float* p1 = xr1 + (j + 1) * 32;
            xn[0][0] = *(const float4*)p0;  xn[0][1] = *(const float4*)(p0 + 4);
            xn[1][0] = *(const float4*)p1;  xn[1][1] = *(const float4*)(p1 + 4);
        }
        // split current x to h/l fragments (registers only)
        v8h Bh[2], Bl[2];
        #pragma unroll
        for (int ti = 0; ti < 2; ++ti) {
            float v[8] = {xc[ti][0].x, xc[ti][0].y, xc[ti][0].z, xc[ti][0].w,
                          xc[ti][1].x, xc[ti][1].y, xc[ti][1].z, xc[ti][1].w};
            v8h h, l;
            #pragma unroll
            for (int e = 0; e < 8; ++e) {
                _Float16 hh = (_Float16)v[e];
                h[e] = hh;
                l[e] = (_Float16)((v[e] - (float)hh) * 2048.0f);
            }
            Bh[ti] = h; Bl[ti] = l;
        }
        // 30 MFMAs
        #pragma unroll
        for (int g = 0; g < 5; ++g) {
            #pragma unroll
            for (int ti = 0; ti < 2; ++ti) {
                aHH[ti][g] = __builtin_amdgcn_mfma_f32_16x16x32_f16(Wh[g], Bh[ti], aHH[ti][g], 0, 0, 0);
                aC[ti][g]  = __builtin_amdgcn_mfma_f32_16x16x32_f16(Wh[g], Bl[ti], aC[ti][g], 0, 0, 0);
                aC[ti][g]  = __builtin_amdgcn_mfma_f32_16x16x32_f16(Wl[g], Bh[ti], aC[ti][g], 0, 0, 0);
            }
        }
        // rotate prefetch
        #pragma unroll
        for (int ti = 0; ti < 2; ++ti) { xc[ti][0] = xn[ti][0]; xc[ti][1] = xn[ti][1]; }
    }

    // combined partial logits for this K-quarter
    v4f part[2][5];
    #pragma unroll
    for (int ti = 0; ti < 2; ++ti)
        #pragma unroll
        for (int g = 0; g < 5; ++g) {
            v4f p;
            #pragma unroll
            for (int r = 0; r < 4; ++r) p[r] = aHH[ti][g][r] + aC[ti][g][r] * (1.0f / 2048.0f);
            part[ti][g] = p;
        }

    // ---- tree reduce over K-quarters (explicit slot index; R7 bug was here) ----
    float4* P4 = (float4*)(sm + P_BASE);
    #define WRITE_P(slot) { _Pragma("unroll") for (int ti = 0; ti < 2; ++ti)          \
        _Pragma("unroll") for (int g = 0; g < 5; ++g) {                               \
            v4f p = part[ti][g];                                                      \
            P4[((ti * 5 + g) * 4 + (slot)) * 64 + lane] = make_float4(p[0],p[1],p[2],p[3]); } }
    #define ADD_P(slot) { _Pragma("unroll") for (int ti = 0; ti < 2; ++ti)            \
        _Pragma("unroll") for (int g = 0; g < 5; ++g) {                               \
            float4 v = P4[((ti * 5 + g) * 4 + (slot)) * 64 + lane];                   \
            part[ti][g][0] += v.x; part[ti][g][1] += v.y;                             \
            part[ti][g][2] += v.z; part[ti][g][3] += v.w; } }

    if (s2 & 1) WRITE_P((s2 >> 1) * 2 + th);     // s2=1 -> slot th; s2=3 -> slot 2+th
    __syncthreads();
    if (!(s2 & 1)) ADD_P((s2 >> 1) * 2 + th);    // s2=0 += s2=1; s2=2 += s2=3
    __syncthreads();
    if (s2 == 2) WRITE_P(2 + th);                // (q2+q3) -> slot 2+th
    __syncthreads();
    if (s2 == 0) ADD_P(2 + th);                  // (q0+q1) += (q2+q3)   [was slot th: bug]

    // s2==0 waves (w=0,1) hold full logits; scatter to la[token][81]
    float* la = sm + LA_BASE;
    if (s2 == 0) {
        #pragma unroll
        for (int ti = 0; ti < 2; ++ti)
            #pragma unroll
            for (int g = 0; g < 5; ++g)
                #pragma unroll
                for (int r = 0; r < 4; ++r)
                    la[(th * 32 + ti * 16 + n) * 81 + g * 16 + q * 4 + r] = part[ti][g][r];
    }
    __syncthreads();

    // ---- per-token dual softmax + hierarchical mask (threads 0..63) ----
    if (tid < 64) {
        const float* lg = la + tid * 81;    // [0..63]=experts, [64..71]=groups
        float* M = sm + M_BASE + tid * 64;
        float* W = sm + W_BASE + tid * 64;

        float gpb[8];
        float gmax = lg[64];
        #pragma unroll
        for (int g = 1; g < 8; ++g) gmax = fmaxf(gmax, lg[64 + g]);
        float gsum = 0.f;
        #pragma unroll
        for (int g = 0; g < 8; ++g) { gpb[g] = __expf(lg[64 + g] - gmax); gsum += gpb[g]; }
        const float ginv = 1.f / gsum;

        float sel[64];
        float wsum = 0.f;
        #pragma unroll
        for (int g = 0; g < 8; ++g) {
            const float gp_ = gpb[g] * ginv;
            float emax = lg[g * 8];
            #pragma unroll
            for (int j = 1; j < 8; ++j) emax = fmaxf(emax, lg[g * 8 + j]);
            float ep[8]; float esum = 0.f;
            #pragma unroll
            for (int j = 0; j < 8; ++j) { ep[j] = __expf(lg[g * 8 + j] - emax); esum += ep[j]; }
            const float einv = 1.f / esum;
            const bool gm = gp_ >= 0.125f;
            #pragma unroll
            for (int j = 0; j < 8; ++j) {
                const float pe = ep[j] * einv;
                const bool v = gm && (pe >= 0.125f);
                const float ww = v ? gp_ * pe : 0.f;
                M[g * 8 + j] = v ? 1.f : 0.f;
                sel[g * 8 + j] = ww;
                wsum += ww;
            }
        }
        const float inv = 1.f / fmaxf(wsum, 1e-9f);
        #pragma unroll
        for (int e = 0; e < 64; ++e) W[e] = sel[e] * inv;
    }
    __syncthreads();

    // ---- coalesced stores: each plane = 64 tok x 64 = 1024 float4 ----
    const float4* M4 = (const float4*)(sm + M_BASE);
    const float4* W4 = (const float4*)(sm + W_BASE);
    float4* o0 = (float4*)(out + (size_t)t0 * 64);
    float4* o1 = (float4*)(out + (size_t)NT * 64 + (size_t)t0 * 64);
    o0[tid]       = M4[tid];
    o0[tid + 512] = M4[tid + 512];
    o1[tid]       = W4[tid];
    o1[tid + 512] = W4[tid + 512];

    #undef WRITE_P
    #undef ADD_P
}

extern "C" void kernel_launch(void* const* d_in, const int* in_sizes, int n_in,
                              void* d_out, int out_size, void* d_ws, size_t ws_size,
                              hipStream_t stream) {
    const float* x  = (const float*)d_in[0];
    const float* gw = (const float*)d_in[1];
    const float* ew = (const float*)d_in[2];
    float* out  = (float*)d_out;
    float* Wbuf = (float*)d_ws;              // 655360 B used

    prep<<<dim3(80),   dim3(256), 0, stream>>>(gw, ew, Wbuf);
    router<<<dim3(NT / 64), dim3(512), 0, stream>>>(x, Wbuf, out);
}